// Round 1
// baseline (346.192 us; speedup 1.0000x reference)
//
#include <hip/hip_runtime.h>

// Problem constants (fixed by reference)
#define B_  8
#define C_  384
#define N_  1600
#define R_  4
#define S_  160
#define HW_ 40

typedef float  f32x4  __attribute__((ext_vector_type(4)));
typedef __bf16 bf16x8 __attribute__((ext_vector_type(8)));

__device__ __forceinline__ unsigned short f2bf(float x){
  __bf16 h = (__bf16)x;                         // RNE
  return __builtin_bit_cast(unsigned short, h);
}

// ---------------------------------------------------------------- norms ----
// invn[mat*N + n] = 1/max(||token||,1e-12); mat 0..7 = feats, 8..39 = refs(r*B+b)
__global__ void norm_kernel(const float* __restrict__ feats,
                            const float* __restrict__ refs,
                            float* __restrict__ invn){
  int gid = blockIdx.x * 256 + threadIdx.x;      // 64000 total
  int mat = gid / N_;
  int n   = gid - mat * N_;
  const float* src = (mat < B_) ? (feats + (size_t)mat * C_ * N_)
                                : (refs  + (size_t)(mat - B_) * C_ * N_);
  float ss = 0.f;
  for (int c = 0; c < C_; ++c){
    float x = src[(size_t)c * N_ + n];
    ss += x * x;
  }
  float nm = sqrtf(ss);
  invn[gid] = 1.f / fmaxf(nm, 1e-12f);
}

// ----------------------------------------------------- transpose/convert ----
// Qb [b][n][c] bf16 normalized; Kb [rb][n][c] bf16 normalized; Vb [rb][c][n] bf16 raw
__global__ void prep_kernel(const float* __restrict__ feats,
                            const float* __restrict__ refs,
                            const float* __restrict__ invn,
                            unsigned short* __restrict__ Qb,
                            unsigned short* __restrict__ Kb,
                            unsigned short* __restrict__ Vb){
  int nt = blockIdx.x, ct = blockIdx.y, mat = blockIdx.z;
  __shared__ float tile[64][65];
  int t = threadIdx.x;
  bool isref = (mat >= B_);
  const float* src = isref ? refs  + (size_t)(mat - B_) * C_ * N_
                           : feats + (size_t)mat * C_ * N_;
#pragma unroll
  for (int i = 0; i < 4; ++i){
    int chunk = t + 256 * i;                      // 0..1023
    int cr = chunk >> 4, n4 = chunk & 15;
    size_t off = (size_t)(ct * 64 + cr) * N_ + nt * 64 + n4 * 4;
    float4 v = *(const float4*)(src + off);
    tile[cr][n4 * 4 + 0] = v.x;  tile[cr][n4 * 4 + 1] = v.y;
    tile[cr][n4 * 4 + 2] = v.z;  tile[cr][n4 * 4 + 3] = v.w;
    if (isref){
      ushort4 o;
      o.x = f2bf(v.x); o.y = f2bf(v.y); o.z = f2bf(v.z); o.w = f2bf(v.w);
      unsigned short* vdst = Vb + (size_t)(mat - B_) * C_ * N_;
      *(ushort4*)(vdst + off) = o;
    }
  }
  __syncthreads();
  unsigned short* dst = isref ? Kb + (size_t)(mat - B_) * N_ * C_
                              : Qb + (size_t)mat * N_ * C_;
  const float* ivp = invn + (size_t)mat * N_ + nt * 64;
#pragma unroll
  for (int i = 0; i < 4; ++i){
    int chunk = t + 256 * i;
    int nr = chunk >> 4, c4 = chunk & 15;
    float iv = ivp[nr];
    ushort4 o;
    o.x = f2bf(tile[c4*4+0][nr] * iv);
    o.y = f2bf(tile[c4*4+1][nr] * iv);
    o.z = f2bf(tile[c4*4+2][nr] * iv);
    o.w = f2bf(tile[c4*4+3][nr] * iv);
    *(ushort4*)(dst + (size_t)(nt*64+nr) * C_ + ct*64 + c4*4) = o;
  }
}

// ------------------------------------------------------------------ mask ----
// jax.image.resize bilinear antialias 160->40: 8-tap triangle, edge-renormalized
__global__ void mask_kernel(const float* __restrict__ sopm,
                            float* __restrict__ maskp){
  int gid = blockIdx.x * 256 + threadIdx.x;       // 12800
  int b = gid / N_, n = gid - b * N_;
  int oy = n / HW_, ox = n - oy * HW_;
  const float* sp = sopm + (size_t)b * S_ * S_;
  float cy = oy * 4 + 1.5f, cx = ox * 4 + 1.5f;
  int y0 = 4*oy - 2; if (y0 < 0) y0 = 0;
  int y1 = 4*oy + 5; if (y1 > S_-1) y1 = S_-1;
  int x0 = 4*ox - 2; if (x0 < 0) x0 = 0;
  int x1 = 4*ox + 5; if (x1 > S_-1) x1 = S_-1;
  float wsy = 0.f, wsx = 0.f;
  for (int j = y0; j <= y1; ++j) wsy += 1.f - fabsf(j - cy) * 0.25f;
  for (int j = x0; j <= x1; ++j) wsx += 1.f - fabsf(j - cx) * 0.25f;
  float acc = 0.f;
  for (int jy = y0; jy <= y1; ++jy){
    float wy = 1.f - fabsf(jy - cy) * 0.25f;
    float rs = 0.f;
    for (int jx = x0; jx <= x1; ++jx)
      rs += (1.f - fabsf(jx - cx) * 0.25f) * sp[jy * S_ + jx];
    acc += wy * rs;
  }
  float val = acc / (wsy * wsx);
  maskp[gid] = (val > 0.3f) ? 1.f : 0.f;
}

// ------------------------------------------------------------- attention ----
// grid 800 = (r*B+b)*25 + qtile (XCD-swizzled). Block: 4 waves, each owns 16 q.
// Swapped QK^T: A=K[m][c], B=Q^T -> D[m][q] (lane: m=(l>>4)*4+reg, q=l&15).
// P -> bf16 -> per-wave LDS -> PV A-frag. No max-tracking (sim<=1 bounds exp).
#define KROW 784                    // 384*2 + 16 pad
#define VROW 80                     // 32*2 + 16 pad
#define PROW 80
#define V_OFF (32 * KROW)           // 25088
#define P_OFF (V_OFF + 384 * VROW)  // 55808
#define LDS_BYTES (P_OFF + 4 * 16 * PROW)  // 60928

__global__ __launch_bounds__(256, 2) void attn_kernel(
    const unsigned short* __restrict__ Qb,
    const unsigned short* __restrict__ Kb,
    const unsigned short* __restrict__ Vb,
    const float* __restrict__ log_tau,
    float* __restrict__ Or)
{
  __shared__ __align__(16) char lds[LDS_BYTES];
  int wg   = blockIdx.x;
  int orig = (wg & 7) * 100 + (wg >> 3);   // XCD-contiguous chunks (800 = 8*100)
  int qt   = orig % 25;
  int rb   = orig / 25;                    // r*B + b
  int b    = rb & 7;
  int lane = threadIdx.x & 63;
  int w    = threadIdx.x >> 6;
  int l15  = lane & 15;
  int lg   = lane >> 4;

  float tau = expf(log_tau[0]);
  tau = fminf(fmaxf(tau, 0.005f), 0.1f);
  float sc = 1.4426950408889634f / tau;    // log2(e)/tau

  // Q fragments stay in registers for the whole kernel (48 VGPR)
  bf16x8 qf[12];
  int qrow = qt * 64 + w * 16 + l15;
  const unsigned short* qp = Qb + ((size_t)b * N_ + qrow) * C_ + lg * 8;
#pragma unroll
  for (int ks = 0; ks < 12; ++ks)
    qf[ks] = *(const bf16x8*)(qp + ks * 32);

  f32x4 o[24];
#pragma unroll
  for (int i = 0; i < 24; ++i) o[i] = (f32x4){0.f,0.f,0.f,0.f};
  float lsum = 0.f;

  const unsigned short* kmat = Kb + (size_t)rb * N_ * C_;
  const unsigned short* vmat = Vb + (size_t)rb * C_ * N_;
  char* Kl = lds;
  char* Vl = lds + V_OFF;
  char* Pl = lds + P_OFF + w * (16 * PROW);

  for (int mt = 0; mt < 50; ++mt){
    // ---- stage K tile [32m][384c] and V tile [384c][32m] (bf16, padded rows)
    {
      const unsigned short* kb = kmat + (size_t)mt * 32 * C_;
#pragma unroll
      for (int i = 0; i < 6; ++i){
        int chunk = threadIdx.x + 256 * i;
        int mr = chunk / 48, c16 = chunk % 48;
        uint4 v = *(const uint4*)(kb + mr * C_ + c16 * 8);
        *(uint4*)(Kl + mr * KROW + c16 * 16) = v;
      }
      const unsigned short* vb = vmat + mt * 32;
#pragma unroll
      for (int i = 0; i < 6; ++i){
        int chunk = threadIdx.x + 256 * i;
        int c = chunk >> 2, m16 = chunk & 3;
        uint4 v = *(const uint4*)(vb + (size_t)c * N_ + m16 * 8);
        *(uint4*)(Vl + c * VROW + m16 * 16) = v;
      }
    }
    __syncthreads();

    // ---- QK^T (swapped): sim[m][q], two 16-m fragments
    f32x4 s0 = {0.f,0.f,0.f,0.f}, s1 = {0.f,0.f,0.f,0.f};
    const char* ka = Kl + l15 * KROW + lg * 16;
#pragma unroll
    for (int ks = 0; ks < 12; ++ks){
      bf16x8 a0 = *(const bf16x8*)(ka + ks * 64);
      bf16x8 a1 = *(const bf16x8*)(ka + 16 * KROW + ks * 64);
      s0 = __builtin_amdgcn_mfma_f32_16x16x32_bf16(a0, qf[ks], s0, 0, 0, 0);
      s1 = __builtin_amdgcn_mfma_f32_16x16x32_bf16(a1, qf[ks], s1, 0, 0, 0);
    }

    // ---- P = exp2((sim-1)*log2e/tau), quantize bf16, accumulate l of rounded P
    ushort4 pw0, pw1;
    float ls = 0.f;
    {
      __bf16 h;
      h = (__bf16)exp2f((s0[0]-1.f)*sc); ls += (float)h; pw0.x = __builtin_bit_cast(unsigned short, h);
      h = (__bf16)exp2f((s0[1]-1.f)*sc); ls += (float)h; pw0.y = __builtin_bit_cast(unsigned short, h);
      h = (__bf16)exp2f((s0[2]-1.f)*sc); ls += (float)h; pw0.z = __builtin_bit_cast(unsigned short, h);
      h = (__bf16)exp2f((s0[3]-1.f)*sc); ls += (float)h; pw0.w = __builtin_bit_cast(unsigned short, h);
      h = (__bf16)exp2f((s1[0]-1.f)*sc); ls += (float)h; pw1.x = __builtin_bit_cast(unsigned short, h);
      h = (__bf16)exp2f((s1[1]-1.f)*sc); ls += (float)h; pw1.y = __builtin_bit_cast(unsigned short, h);
      h = (__bf16)exp2f((s1[2]-1.f)*sc); ls += (float)h; pw1.z = __builtin_bit_cast(unsigned short, h);
      h = (__bf16)exp2f((s1[3]-1.f)*sc); ls += (float)h; pw1.w = __builtin_bit_cast(unsigned short, h);
    }
    lsum += ls;
    // per-wave P round-trip: [q][m] rows, 80B stride
    *(ushort4*)(Pl + l15 * PROW + lg * 8)      = pw0;   // m = lg*4..+3
    *(ushort4*)(Pl + l15 * PROW + 32 + lg * 8) = pw1;   // m = 16+lg*4..+3
    asm volatile("s_waitcnt lgkmcnt(0)" ::: "memory");
    bf16x8 pa = *(const bf16x8*)(Pl + l15 * PROW + lg * 16); // P[q=l15][m=lg*8..+7]

    // ---- PV: O[q][c] += P * V  (24 c-fragments)
    const char* va = Vl + l15 * VROW + lg * 16;
#pragma unroll
    for (int cf = 0; cf < 24; ++cf){
      bf16x8 vf = *(const bf16x8*)(va + cf * (16 * VROW));
      o[cf] = __builtin_amdgcn_mfma_f32_16x16x32_bf16(pa, vf, o[cf], 0, 0, 0);
    }
    __syncthreads();
  }

  // ---- finalize: l across lane groups (q = l15 layout), move to D layout
  lsum += __shfl_xor(lsum, 16, 64);
  lsum += __shfl_xor(lsum, 32, 64);
  float invl[4];
#pragma unroll
  for (int rg = 0; rg < 4; ++rg){
    float lv = __shfl(lsum, lg * 4 + rg, 64);   // lane (lg*4+rg) holds q=lg*4+rg
    invl[rg] = 1.f / lv;
  }
  int qbase = qt * 64 + w * 16 + lg * 4;
  float* op = Or + ((size_t)rb * N_ + qbase) * C_ + l15;
#pragma unroll
  for (int cf = 0; cf < 24; ++cf){
#pragma unroll
    for (int rg = 0; rg < 4; ++rg){
      op[(size_t)rg * C_ + cf * 16] = o[cf][rg] * invl[rg];
    }
  }
}

// --------------------------------------------------------------- combine ----
// out[b][c][n] = feats + mask*alpha*(sum_r Or/4 - feats); transpose [n][c]->[c][n]
__global__ void combine_kernel(const float* __restrict__ Or,
                               const float* __restrict__ feats,
                               const float* __restrict__ maskp,
                               const float* __restrict__ alpha_raw,
                               float* __restrict__ out){
  int nt = blockIdx.x, ct = blockIdx.y, b = blockIdx.z;
  __shared__ float tile[64][65];
  float alpha = 1.f / (1.f + expf(-alpha_raw[0]));
  int t = threadIdx.x;
#pragma unroll
  for (int i = 0; i < 4; ++i){
    int chunk = t + 256 * i;
    int nr = chunk >> 4, c4 = chunk & 15;
    size_t base = ((size_t)b * N_ + nt * 64 + nr) * C_ + ct * 64 + c4 * 4;
    float4 s = {0.f,0.f,0.f,0.f};
#pragma unroll
    for (int r = 0; r < 4; ++r){
      float4 v = *(const float4*)(Or + (size_t)r * B_ * N_ * C_ + base);
      s.x += v.x; s.y += v.y; s.z += v.z; s.w += v.w;
    }
    tile[nr][c4*4+0] = s.x; tile[nr][c4*4+1] = s.y;
    tile[nr][c4*4+2] = s.z; tile[nr][c4*4+3] = s.w;
  }
  __syncthreads();
#pragma unroll
  for (int i = 0; i < 4; ++i){
    int chunk = t + 256 * i;
    int cr = chunk >> 4, n4 = chunk & 15;
    size_t fb = ((size_t)b * C_ + ct * 64 + cr) * N_ + nt * 64 + n4 * 4;
    float4 f  = *(const float4*)(feats + fb);
    float4 mk = *(const float4*)(maskp + (size_t)b * N_ + nt * 64 + n4 * 4);
    float4 ov;
    ov.x = f.x + mk.x * alpha * (tile[n4*4+0][cr] * 0.25f - f.x);
    ov.y = f.y + mk.y * alpha * (tile[n4*4+1][cr] * 0.25f - f.y);
    ov.z = f.z + mk.z * alpha * (tile[n4*4+2][cr] * 0.25f - f.z);
    ov.w = f.w + mk.w * alpha * (tile[n4*4+3][cr] * 0.25f - f.w);
    *(float4*)(out + fb) = ov;
  }
}

// ws-too-small sentinel: recognizable absmax ~1e6
__global__ void poison_kernel(float* out, int n){
  int i = blockIdx.x * 256 + threadIdx.x;
  if (i < n) out[i] = 1.0e6f;
}

extern "C" void kernel_launch(void* const* d_in, const int* in_sizes, int n_in,
                              void* d_out, int out_size, void* d_ws, size_t ws_size,
                              hipStream_t stream){
  const float* feats     = (const float*)d_in[0];
  const float* refs      = (const float*)d_in[1];
  const float* sopm      = (const float*)d_in[2];
  const float* log_tau   = (const float*)d_in[3];
  const float* alpha_raw = (const float*)d_in[4];
  float* out = (float*)d_out;

  const size_t SZ_INVN = (size_t)(1 + R_) * B_ * N_ * 4;   //   256,000
  const size_t SZ_MASK = (size_t)B_ * N_ * 4;              //    51,200
  const size_t SZ_QB   = (size_t)B_ * N_ * C_ * 2;         // 9,830,400
  const size_t SZ_KB   = (size_t)R_ * B_ * N_ * C_ * 2;    // 39,321,600
  const size_t SZ_VB   = SZ_KB;
  const size_t SZ_OR   = (size_t)R_ * B_ * N_ * C_ * 4;    // 78,643,200
  const size_t need = SZ_INVN + SZ_MASK + SZ_QB + SZ_KB + SZ_VB + SZ_OR;

  if (ws_size < need){
    poison_kernel<<<(out_size + 255) / 256, 256, 0, stream>>>(out, out_size);
    return;
  }
  char* ws = (char*)d_ws;
  float*          invn  = (float*)ws;
  float*          maskp = (float*)(ws + SZ_INVN);
  unsigned short* Qb    = (unsigned short*)(ws + SZ_INVN + SZ_MASK);
  unsigned short* Kb    = (unsigned short*)(ws + SZ_INVN + SZ_MASK + SZ_QB);
  unsigned short* Vb    = (unsigned short*)(ws + SZ_INVN + SZ_MASK + SZ_QB + SZ_KB);
  float*          Or    = (float*)(ws + SZ_INVN + SZ_MASK + SZ_QB + SZ_KB + SZ_VB);

  norm_kernel   <<<250, 256, 0, stream>>>(feats, refs, invn);
  mask_kernel   <<<50, 256, 0, stream>>>(sopm, maskp);
  prep_kernel   <<<dim3(25, 6, 40), 256, 0, stream>>>(feats, refs, invn, Qb, Kb, Vb);
  attn_kernel   <<<800, 256, 0, stream>>>(Qb, Kb, Vb, log_tau, Or);
  combine_kernel<<<dim3(25, 6, 8), 256, 0, stream>>>(Or, feats, maskp, alpha_raw, out);
}